// Round 4
// baseline (111.292 us; speedup 1.0000x reference)
//
#include <hip/hip_runtime.h>
#include <hip/hip_fp16.h>

// Problem constants (from reference setup_inputs)
#define N_TF    1024
#define N_GENES 20000
#define WW      4
#define FANIN   16
#define BATCH   128
#define EPG     (WW * FANIN)            // 64 edges per gene
#define NNZ1    (N_GENES * EPG)

// fused geometry: 1 gene per wave, 16 waves (1024 thr) per block
#define GPB      16
#define NTHREADS 1024
#define NBLK     (N_GENES / GPB)        // 1250
#define YROW     (BATCH + 2)            // yt row stride (floats)

typedef unsigned int uint32;

// ---------------------------------------------------------------------------
// Batched fast tanh for 2 values: 2x exp + ONE rcp (exact identity, fp32).
// tanh(x) = 1 - 2/(1+e^{2x}); shared rcp(da*db). Robust at +/-inf.
__device__ __forceinline__ float2 fast_tanh2(float a, float b) {
    const float ta = __expf(2.0f * a);
    const float tb = __expf(2.0f * b);
    const float da = ta + 1.0f;
    const float db = tb + 1.0f;
    const float r  = __builtin_amdgcn_rcpf(da * db);
    return make_float2(fmaf(-2.0f * db, r, 1.0f),
                       fmaf(-2.0f * da, r, 1.0f));
}

// ---------------------------------------------------------------------------
// features [B=128][N_TF=1024] fp32 -> xh [N_TF=1024][B=128] fp16 (256 B rows)
__global__ __launch_bounds__(256) void transpose_cvt_kernel(
    const float* __restrict__ in, __half* __restrict__ out)
{
    __shared__ float tile[32][33];
    const int bx = blockIdx.x;            // N_TF tile 0..31
    const int by = blockIdx.y;            // B tile 0..3
    const int tx = threadIdx.x;           // 0..31
    const int ty = threadIdx.y;           // 0..7
#pragma unroll
    for (int k = 0; k < 32; k += 8)
        tile[ty + k][tx] = in[(by * 32 + ty + k) * N_TF + bx * 32 + tx];
    __syncthreads();
    const int b = by * 32 + tx;
#pragma unroll
    for (int k = 0; k < 32; k += 8) {
        const int tf = bx * 32 + ty + k;
        out[tf * BATCH + b] = __float2half(tile[tx][ty + k]);
    }
}

// ---------------------------------------------------------------------------
// Fused 3-layer kernel. 1 gene per wave, wave-uniform gene index.
// DATAPATH = verified 109.8us baseline (lane owns batch pair 2*lane,2*lane+1;
// 64 x 4B gathers/gene via SGPR row index + lane*4 offset; fp16 hfma2 accum
// in EXACT edge order 0..63 -> bitwise-identical output to the baseline).
// ONLY change vs baseline: the two 32-deep gather batches are merged into
// ONE 64-deep batch (all 16 s_load_dwordx4 of indices first, then all 64
// gathers issued back-to-back, then weights+consume). This removes the
// inter-half vmcnt drain bubble; no new semantics, pure reordering.
__global__ __launch_bounds__(NTHREADS, 4) void fused_kernel(
    const __half* __restrict__ xh,     // [N_TF][128] fp16
    const int*    __restrict__ in1,    // [NNZ1]
    const float*  __restrict__ w1,     // [NNZ1]
    const float*  __restrict__ b1,     // [M]
    const float*  __restrict__ w2,     // [M*W]
    const float*  __restrict__ b2,     // [M]
    const float*  __restrict__ w3,     // [N_GENES*W]
    const float*  __restrict__ b3,     // [N_GENES]
    float*        __restrict__ out)    // [B][N_GENES]
{
    __shared__ float yt[GPB * YROW];   // 16*130*4 = 8320 B

    const int tid  = threadIdx.x;
    const int wid  = __builtin_amdgcn_readfirstlane(tid >> 6);   // uniform
    const int lane = tid & 63;
    const int g    = blockIdx.x * GPB + wid;                     // uniform
    const int voff = lane << 2;        // byte offset of this lane's __half2
    const char* xb = (const char*)xh;

    const uint4*  __restrict__ ig = (const uint4*)(in1 + g * EPG);  // 16 x uint4
    const float4* __restrict__ wg = (const float4*)(w1 + g * EPG);  // 16 x float4

    // ---- Phase A: all 64 edge indices into SGPRs (16 x s_load_dwordx4) ----
    uint32 idx[64];
#pragma unroll
    for (int k = 0; k < 16; ++k) {
        const uint4 iq = ig[k];
        idx[k * 4 + 0] = iq.x;  idx[k * 4 + 1] = iq.y;
        idx[k * 4 + 2] = iq.z;  idx[k * 4 + 3] = iq.w;
    }

    // ---- Phase B: issue all 64 gathers (64-deep in flight) ----------------
    __half2 xv[64];
#pragma unroll
    for (int t = 0; t < 64; ++t)
        xv[t] = *(const __half2*)(xb + (((size_t)idx[t]) << 8) + voff);

    // ---- Phase C: weights + consume, EXACT baseline edge order 0..63 ------
    __half2 acc[WW];
    const __half2 hz = __float2half2_rn(0.0f);
#pragma unroll
    for (int i = 0; i < WW; ++i) acc[i] = hz;

#pragma unroll
    for (int k = 0; k < 16; ++k) {
        const float4 wq = wg[k];                       // s_load_dwordx4
        const int t0 = k * 4;                          // edges t0..t0+3
        acc[(t0 + 0) >> 4] = __hfma2(__float2half2_rn(wq.x), xv[t0 + 0],
                                     acc[(t0 + 0) >> 4]);
        acc[(t0 + 1) >> 4] = __hfma2(__float2half2_rn(wq.y), xv[t0 + 1],
                                     acc[(t0 + 1) >> 4]);
        acc[(t0 + 2) >> 4] = __hfma2(__float2half2_rn(wq.z), xv[t0 + 2],
                                     acc[(t0 + 2) >> 4]);
        acc[(t0 + 3) >> 4] = __hfma2(__float2half2_rn(wq.w), xv[t0 + 3],
                                     acc[(t0 + 3) >> 4]);
    }

    float2 h1[WW];
#pragma unroll
    for (int i = 0; i < WW; ++i) {
        const float  bb = b1[g * WW + i];                            // s_load
        const float2 af = __half22float2(acc[i]);
        h1[i] = fast_tanh2(af.x + bb, af.y + bb);
    }

    // ---- Layer 2: dense 4x4 (weights via s_load) ---------------------------
    float2 h2[WW];
#pragma unroll
    for (int i = 0; i < WW; ++i) {
        const float4 w  = *(const float4*)(w2 + g * 16 + i * 4);     // s_load
        const float  bb = b2[g * WW + i];
        const float sx = bb + w.x * h1[0].x + w.y * h1[1].x
                            + w.z * h1[2].x + w.w * h1[3].x;
        const float sy = bb + w.x * h1[0].y + w.y * h1[1].y
                            + w.z * h1[2].y + w.w * h1[3].y;
        h2[i] = fast_tanh2(sx, sy);
    }

    // ---- Layer 3: sum 4 nodes ----------------------------------------------
    const float4 wv3 = *(const float4*)(w3 + g * 4);                 // s_load
    const float  bv  = b3[g];
    const float yx = bv + wv3.x * h2[0].x + wv3.y * h2[1].x
                        + wv3.z * h2[2].x + wv3.w * h2[3].x;
    const float yy = bv + wv3.x * h2[0].y + wv3.y * h2[1].y
                        + wv3.z * h2[2].y + wv3.w * h2[3].y;

    // ---- stash to LDS [gene][batch] ----------------------------------------
    float2* ytw = (float2*)(yt + wid * YROW);
    ytw[lane] = make_float2(yx, yy);

    __syncthreads();

    // ---- coalesced store: 16 consecutive genes per batch row (64 B runs) ---
    const int g0 = blockIdx.x * GPB;
#pragma unroll
    for (int it = 0; it < (BATCH * GPB) / NTHREADS; ++it) {          // 2
        const int idx2 = it * NTHREADS + tid;
        const int gq   = idx2 & (GPB - 1);
        const int b    = idx2 >> 4;
        out[b * N_GENES + g0 + gq] = yt[gq * YROW + b];
    }
}

// ---------------------------------------------------------------------------
extern "C" void kernel_launch(void* const* d_in, const int* in_sizes, int n_in,
                              void* d_out, int out_size, void* d_ws, size_t ws_size,
                              hipStream_t stream)
{
    // order: features, w1, b1, w2, b2, w3, b3, out1, in1, out2, in2, out3, in3
    const float* features = (const float*)d_in[0];
    const float* w1 = (const float*)d_in[1];
    const float* b1 = (const float*)d_in[2];
    const float* w2 = (const float*)d_in[3];
    const float* b2 = (const float*)d_in[4];
    const float* w3 = (const float*)d_in[5];
    const float* b3 = (const float*)d_in[6];
    const int*   in1 = (const int*)d_in[8];
    float* out = (float*)d_out;

    __half* xh = (__half*)d_ws;                  // [1024][128] fp16 = 256 KiB

    hipLaunchKernelGGL(transpose_cvt_kernel, dim3(32, 4), dim3(32, 8), 0, stream,
                       features, xh);
    hipLaunchKernelGGL(fused_kernel, dim3(NBLK), dim3(NTHREADS), 0, stream,
                       xh, in1, w1, b1, w2, b2, w3, b3, out);
}

// Round 5
// 110.023 us; speedup vs baseline: 1.0115x; 1.0115x over previous
//
#include <hip/hip_runtime.h>
#include <hip/hip_fp16.h>

// Problem constants (from reference setup_inputs)
#define N_TF    1024
#define N_GENES 20000
#define WW      4
#define FANIN   16
#define BATCH   128
#define EPG     (WW * FANIN)            // 64 edges per gene
#define NNZ1    (N_GENES * EPG)

// fused geometry: 1 gene per wave, 16 waves (1024 thr) per block
#define GPB      16
#define NTHREADS 1024
#define NBLK     (N_GENES / GPB)        // 1250
#define YROW     (BATCH + 2)            // yt row stride (floats)

typedef unsigned int uint32;

// ---------------------------------------------------------------------------
// Batched fast tanh for 2 values: 2x exp + ONE rcp (exact identity, fp32).
// tanh(x) = 1 - 2/(1+e^{2x}); shared rcp(da*db). Robust at +/-inf.
__device__ __forceinline__ float2 fast_tanh2(float a, float b) {
    const float ta = __expf(2.0f * a);
    const float tb = __expf(2.0f * b);
    const float da = ta + 1.0f;
    const float db = tb + 1.0f;
    const float r  = __builtin_amdgcn_rcpf(da * db);
    return make_float2(fmaf(-2.0f * db, r, 1.0f),
                       fmaf(-2.0f * da, r, 1.0f));
}

// ---------------------------------------------------------------------------
// features [B=128][N_TF=1024] fp32 -> xh [N_TF=1024][B=128] fp16 (256 B rows)
__global__ __launch_bounds__(256) void transpose_cvt_kernel(
    const float* __restrict__ in, __half* __restrict__ out)
{
    __shared__ float tile[32][33];
    const int bx = blockIdx.x;            // N_TF tile 0..31
    const int by = blockIdx.y;            // B tile 0..3
    const int tx = threadIdx.x;           // 0..31
    const int ty = threadIdx.y;           // 0..7
#pragma unroll
    for (int k = 0; k < 32; k += 8)
        tile[ty + k][tx] = in[(by * 32 + ty + k) * N_TF + bx * 32 + tx];
    __syncthreads();
    const int b = by * 32 + tx;
#pragma unroll
    for (int k = 0; k < 32; k += 8) {
        const int tf = bx * 32 + ty + k;
        out[tf * BATCH + b] = __float2half(tile[tx][ty + k]);
    }
}

// ---------------------------------------------------------------------------
// Fused 3-layer kernel. 1 gene per wave, wave-uniform gene index.
// DATAPATH = verified baseline (lane owns batch pair 2*lane,2*lane+1;
// 64 x 4B gathers/gene via SGPR row index + lane*4 offset; fp16 hfma2 accum
// in EXACT edge order 0..63 -> bitwise-identical output to the baseline).
// ONLY change vs the verified round-3/round-0 kernels: gathers issued in
// FOUR 16-deep chunks (chunk == node), shrinking the peak VGPR live set to
// xv[16] (~40 regs total), and __launch_bounds__(1024, 8) caps VGPR at 64
// -> 2 blocks/CU = 32 waves/CU (was 16). Latency hiding moves from ILP to
// TLP; per-CU outstanding loads unchanged (32 waves x 16 = 16 x 32).
__global__ __launch_bounds__(NTHREADS, 8) void fused_kernel(
    const __half* __restrict__ xh,     // [N_TF][128] fp16
    const int*    __restrict__ in1,    // [NNZ1]
    const float*  __restrict__ w1,     // [NNZ1]
    const float*  __restrict__ b1,     // [M]
    const float*  __restrict__ w2,     // [M*W]
    const float*  __restrict__ b2,     // [M]
    const float*  __restrict__ w3,     // [N_GENES*W]
    const float*  __restrict__ b3,     // [N_GENES]
    float*        __restrict__ out)    // [B][N_GENES]
{
    __shared__ float yt[GPB * YROW];   // 16*130*4 = 8320 B

    const int tid  = threadIdx.x;
    const int wid  = __builtin_amdgcn_readfirstlane(tid >> 6);   // uniform
    const int lane = tid & 63;
    const int g    = blockIdx.x * GPB + wid;                     // uniform
    const int voff = lane << 2;        // byte offset of this lane's __half2
    const char* xb = (const char*)xh;

    const uint4*  __restrict__ ig = (const uint4*)(in1 + g * EPG);  // 16 x uint4
    const float4* __restrict__ wg = (const float4*)(w1 + g * EPG);  // 16 x float4

    __half2 acc[WW];
    const __half2 hz = __float2half2_rn(0.0f);
#pragma unroll
    for (int i = 0; i < WW; ++i) acc[i] = hz;

    // ---- Layer 1: four 16-deep gather chunks (chunk c4 == node c4) --------
#pragma unroll
    for (int c4 = 0; c4 < 4; ++c4) {
        // indices for edges c4*16 .. c4*16+15 (4 x s_load_dwordx4)
        uint32 idx[16];
#pragma unroll
        for (int k = 0; k < 4; ++k) {
            const uint4 iq = ig[c4 * 4 + k];
            idx[k * 4 + 0] = iq.x;  idx[k * 4 + 1] = iq.y;
            idx[k * 4 + 2] = iq.z;  idx[k * 4 + 3] = iq.w;
        }
        // issue 16 gathers (16-deep in flight per wave; TLP does the rest)
        __half2 xv[16];
#pragma unroll
        for (int t = 0; t < 16; ++t)
            xv[t] = *(const __half2*)(xb + (((size_t)idx[t]) << 8) + voff);
        // weights + consume, exact edge order
#pragma unroll
        for (int k = 0; k < 4; ++k) {
            const float4 wq = wg[c4 * 4 + k];              // s_load_dwordx4
            const int t0 = k * 4;
            acc[c4] = __hfma2(__float2half2_rn(wq.x), xv[t0 + 0], acc[c4]);
            acc[c4] = __hfma2(__float2half2_rn(wq.y), xv[t0 + 1], acc[c4]);
            acc[c4] = __hfma2(__float2half2_rn(wq.z), xv[t0 + 2], acc[c4]);
            acc[c4] = __hfma2(__float2half2_rn(wq.w), xv[t0 + 3], acc[c4]);
        }
    }

    float2 h1[WW];
#pragma unroll
    for (int i = 0; i < WW; ++i) {
        const float  bb = b1[g * WW + i];                            // s_load
        const float2 af = __half22float2(acc[i]);
        h1[i] = fast_tanh2(af.x + bb, af.y + bb);
    }

    // ---- Layer 2: dense 4x4 (weights via s_load) ---------------------------
    float2 h2[WW];
#pragma unroll
    for (int i = 0; i < WW; ++i) {
        const float4 w  = *(const float4*)(w2 + g * 16 + i * 4);     // s_load
        const float  bb = b2[g * WW + i];
        const float sx = bb + w.x * h1[0].x + w.y * h1[1].x
                            + w.z * h1[2].x + w.w * h1[3].x;
        const float sy = bb + w.x * h1[0].y + w.y * h1[1].y
                            + w.z * h1[2].y + w.w * h1[3].y;
        h2[i] = fast_tanh2(sx, sy);
    }

    // ---- Layer 3: sum 4 nodes ----------------------------------------------
    const float4 wv3 = *(const float4*)(w3 + g * 4);                 // s_load
    const float  bv  = b3[g];
    const float yx = bv + wv3.x * h2[0].x + wv3.y * h2[1].x
                        + wv3.z * h2[2].x + wv3.w * h2[3].x;
    const float yy = bv + wv3.x * h2[0].y + wv3.y * h2[1].y
                        + wv3.z * h2[2].y + wv3.w * h2[3].y;

    // ---- stash to LDS [gene][batch] ----------------------------------------
    float2* ytw = (float2*)(yt + wid * YROW);
    ytw[lane] = make_float2(yx, yy);

    __syncthreads();

    // ---- coalesced store: 16 consecutive genes per batch row (64 B runs) ---
    const int g0 = blockIdx.x * GPB;
#pragma unroll
    for (int it = 0; it < (BATCH * GPB) / NTHREADS; ++it) {          // 2
        const int idx2 = it * NTHREADS + tid;
        const int gq   = idx2 & (GPB - 1);
        const int b    = idx2 >> 4;
        out[b * N_GENES + g0 + gq] = yt[gq * YROW + b];
    }
}

// ---------------------------------------------------------------------------
extern "C" void kernel_launch(void* const* d_in, const int* in_sizes, int n_in,
                              void* d_out, int out_size, void* d_ws, size_t ws_size,
                              hipStream_t stream)
{
    // order: features, w1, b1, w2, b2, w3, b3, out1, in1, out2, in2, out3, in3
    const float* features = (const float*)d_in[0];
    const float* w1 = (const float*)d_in[1];
    const float* b1 = (const float*)d_in[2];
    const float* w2 = (const float*)d_in[3];
    const float* b2 = (const float*)d_in[4];
    const float* w3 = (const float*)d_in[5];
    const float* b3 = (const float*)d_in[6];
    const int*   in1 = (const int*)d_in[8];
    float* out = (float*)d_out;

    __half* xh = (__half*)d_ws;                  // [1024][128] fp16 = 256 KiB

    hipLaunchKernelGGL(transpose_cvt_kernel, dim3(32, 4), dim3(32, 8), 0, stream,
                       features, xh);
    hipLaunchKernelGGL(fused_kernel, dim3(NBLK), dim3(NTHREADS), 0, stream,
                       xh, in1, w1, b1, w2, b2, w3, b3, out);
}